// Round 17
// baseline (118.683 us; speedup 1.0000x reference)
//
#include <hip/hip_runtime.h>
#include <hip/hip_bf16.h>
#include <stdint.h>

#define DEVI __device__ __forceinline__

typedef unsigned short u16;
typedef __attribute__((ext_vector_type(8))) short short8;
typedef __attribute__((ext_vector_type(8))) __bf16 bf16x8;
typedef __attribute__((ext_vector_type(4))) float f32x4;
typedef __attribute__((ext_vector_type(4))) uint32_t u32x4;

// ---------- small helpers ----------
DEVI u16 f2b(float f) {
  __hip_bfloat16 h = __float2bfloat16(f);
  return __builtin_bit_cast(u16, h);
}
DEVI float b2f(u16 u) {
  union { float f; uint32_t i; } v;
  v.i = ((uint32_t)u) << 16;
  return v.f;
}

DEVI f32x4 mfma16(short8 a, short8 b, f32x4 c) {
  return __builtin_amdgcn_mfma_f32_16x16x32_bf16(
      __builtin_bit_cast(bf16x8, a), __builtin_bit_cast(bf16x8, b), c, 0, 0, 0);
}

// async global->LDS, 16B per lane; LDS dest = wave-uniform base + lane*16
DEVI void gload_lds16(const u16* g, u16* l) {
  __builtin_amdgcn_global_load_lds(
      (const __attribute__((address_space(1))) uint32_t*)g,
      (__attribute__((address_space(3))) uint32_t*)l, 16, 0, 0);
}

// Swizzled ds_read_b128 of an MFMA fragment from a [rows][64] bf16 tile
DEVI short8 lds_frag(const u16* base, int row, int col16) {
  int byte = (row << 7) ^ (col16 << 4) ^ ((row & 7) << 4);
  return *(const short8*)((const char*)base + byte);
}

// v_cvt_pk_bf16_f32: dst.lo = bf16(lo), dst.hi = bf16(hi)
DEVI uint32_t cvtpk(float lo, float hi) {
  uint32_t r;
  asm("v_cvt_pk_bf16_f32 %0, %1, %2" : "=v"(r) : "v"(lo), "v"(hi));
  return r;
}
// NOTE: operands must hold DISTINCT registers (same-value operands get
// register-coalesced -> self-swap -> silent corruption; round-4 bug).
DEVI void swap32(uint32_t& a, uint32_t& b) {
  asm("v_permlane32_swap_b32 %0, %1" : "+v"(a), "+v"(b));
}
DEVI void swap16(uint32_t& a, uint32_t& b) {
  asm("v_permlane16_swap_b32 %0, %1" : "+v"(a), "+v"(b));
}

// ---------- fp32 -> bf16 conversion of inputs + RoPE table build ----------
DEVI ushort4 cvt4(float4 v) {
  ushort4 o;
  o.x = f2b(v.x); o.y = f2b(v.y); o.z = f2b(v.z); o.w = f2b(v.w);
  return o;
}
DEVI ushort4 cvt4s(float4 v, float s) {
  ushort4 o;
  o.x = f2b(v.x * s); o.y = f2b(v.y * s); o.z = f2b(v.z * s); o.w = f2b(v.w * s);
  return o;
}

__global__ void cvt_kernel(const float4* __restrict__ x, const float4* __restrict__ wq,
                           const float4* __restrict__ wk, const float4* __restrict__ wv,
                           ushort4* __restrict__ xb, ushort4* __restrict__ wqb,
                           ushort4* __restrict__ wkb, ushort4* __restrict__ wvb,
                           float2* __restrict__ ropeT) {
  int t = blockIdx.x * blockDim.x + threadIdx.x;
  int stride = gridDim.x * blockDim.x;
  // wq pre-scaled by 0.125*log2(e): RoPE is linear, so the attention scale
  // (and the exp2 conversion factor) commutes into the Q weights.
  const float QS = 0.18033688011112042f;
  for (int i = t; i < 1048576; i += stride) xb[i]  = cvt4(x[i]);
  for (int i = t; i < 1048576; i += stride) wqb[i] = cvt4s(wq[i], QS);
  for (int i = t; i < 262144;  i += stride) wkb[i] = cvt4(wk[i]);
  for (int i = t; i < 262144;  i += stride) wvb[i] = cvt4(wv[i]);
  // RoPE table: [s 2048][ip 32] -> (cos, sin) of s * 10000^(-ip/32).
  // Lives in the (currently dead) AOb region; attn overwrites it later.
  for (int i = t; i < 65536; i += stride) {
    int s = i >> 5, ip = i & 31;
    float sn, cs;
    sincosf((float)s * exp2f(-(float)ip * 0.41524101186092034f), &sn, &cs);
    ropeT[i] = float2{cs, sn};
  }
}

// ---------- QKV projection GEMM, 128x64 tile, double-buffered + counted vmcnt ----------
// Staging loads stay in flight across barriers (vmcnt(6), never 0 mid-loop);
// removes the per-K-step full drain of the __syncthreads structure (the
// documented ~20% stall). Table-driven RoPE epilogue.
__global__ __launch_bounds__(256) void qkv_gemm(
    const u16* __restrict__ X, const u16* __restrict__ WQ,
    const u16* __restrict__ WK, const u16* __restrict__ WV,
    const float2* __restrict__ ropeT,
    u16* __restrict__ Qo, u16* __restrict__ Ko, u16* __restrict__ VTo) {
  __shared__ __align__(16) u16 As[2][128 * 64];
  __shared__ __align__(16) u16 Bs[2][64 * 64];
  const int tid = threadIdx.x;
  const int l = tid & 63, w = tid >> 6;
  const int wm = w >> 1, wn = w & 1;
  const int bn = blockIdx.x, bm = blockIdx.y;
  const int g = l >> 4, lc = l & 15;

  const u16* Wsrc;
  int nbase;
  if (bn < 32)      { Wsrc = WQ; nbase = bn * 64; }
  else if (bn < 40) { Wsrc = WK; nbase = bn * 64 - 2048; }
  else              { Wsrc = WV; nbase = bn * 64 - 2560; }

  f32x4 acc[4][2];
#pragma unroll
  for (int i = 0; i < 4; ++i)
#pragma unroll
    for (int j = 0; j < 2; ++j) acc[i][j] = f32x4{0.f, 0.f, 0.f, 0.f};

  const u16* Abase = X + (size_t)bm * 128 * 2048;

  // staging: 4 A-chunks + 2 B-chunks per thread = 6 loads per K-step
  const int sr = tid >> 3;                 // 0..31 within the 256-row span
  const int sc = (tid & 7) ^ (sr & 7);     // pre-swizzled 16B column

#define QKV_STAGE(kt, buf)                                                      \
  {                                                                             \
    _Pragma("unroll")                                                           \
    for (int i = 0; i < 4; ++i) {                                               \
      int p = i * 256 + tid;                                                    \
      int r = p >> 3;                                                           \
      int c = (p & 7) ^ (r & 7);                                                \
      gload_lds16(Abase + (size_t)r * 2048 + (kt) * 64 + c * 8, As[buf] + p * 8); \
    }                                                                           \
    _Pragma("unroll")                                                           \
    for (int i = 0; i < 2; ++i) {                                               \
      int p = i * 256 + tid;                                                    \
      int r = p >> 3;                                                           \
      int c = (p & 7) ^ (r & 7);                                                \
      gload_lds16(Wsrc + (size_t)(nbase + r) * 2048 + (kt) * 64 + c * 8, Bs[buf] + p * 8); \
    }                                                                           \
  }

  QKV_STAGE(0, 0);

  for (int kt = 0; kt < 32; ++kt) {
    const int b = kt & 1;
    __builtin_amdgcn_s_barrier();   // prev compute done reading buf[b^1]
    __builtin_amdgcn_sched_barrier(0);
    if (kt + 1 < 32) {
      QKV_STAGE(kt + 1, b ^ 1);
      asm volatile("s_waitcnt vmcnt(6)" ::: "memory");  // stage(kt) landed
    } else {
      asm volatile("s_waitcnt vmcnt(0)" ::: "memory");
    }
    __builtin_amdgcn_s_barrier();   // every wave's stage(kt) portion visible
    __builtin_amdgcn_sched_barrier(0);

#pragma unroll
    for (int kk = 0; kk < 2; ++kk) {
      short8 af[4], bfr[2];
#pragma unroll
      for (int mi = 0; mi < 4; ++mi)
        af[mi] = lds_frag(As[b], wm * 64 + mi * 16 + lc, kk * 4 + g);
#pragma unroll
      for (int ni = 0; ni < 2; ++ni)
        bfr[ni] = lds_frag(Bs[b], wn * 32 + ni * 16 + lc, kk * 4 + g);
#pragma unroll
      for (int mi = 0; mi < 4; ++mi)
#pragma unroll
        for (int ni = 0; ni < 2; ++ni)
          acc[mi][ni] = mfma16(af[mi], bfr[ni], acc[mi][ni]);
    }
  }
#undef QKV_STAGE

#pragma unroll
  for (int mi = 0; mi < 4; ++mi) {
    int srow0 = bm * 128 + wm * 64 + mi * 16 + g * 4;
#pragma unroll
    for (int ni = 0; ni < 2; ++ni) {
      int n = nbase + wn * 32 + ni * 16 + lc;
      f32x4 v = acc[mi][ni];
      if (bn < 40) {
        // fused RoPE: pair (2i, 2i+1) within head; partner value in lane lc^1
        int ip = (n & 63) >> 1;
        bool odd = (n & 1);
#pragma unroll
        for (int r = 0; r < 4; ++r) {
          float own = v[r];
          float par = __shfl_xor(own, 1);
          float2 cssn = ropeT[(srow0 + r) * 32 + ip];
          float res = odd ? fmaf(par, cssn.y, own * cssn.x)
                          : fmaf(own, cssn.x, -(par * cssn.y));
          if (bn < 32) Qo[(size_t)(srow0 + r) * 2048 + n] = f2b(res);
          else         Ko[(size_t)(srow0 + r) * 512 + n]  = f2b(res);
        }
      } else {
        ushort4 pk;
        pk.x = f2b(v[0]); pk.y = f2b(v[1]); pk.z = f2b(v[2]); pk.w = f2b(v[3]);
        *(ushort4*)(VTo + (size_t)n * 2048 + srow0) = pk;
      }
    }
  }
}

// ---------- causal flash attention: 8-wave in-block split-K, NO-MAX softmax ----------
// r12 hot loop verbatim + wo-conversion prologue (r16).
DEVI void stage_pair(const u16* __restrict__ Kb, const u16* __restrict__ VTb,
                     u16* base, int kvh, int t0, int t1, int tid) {
  int r = tid >> 3;
  int c = (tid & 7) ^ (r & 7);
  gload_lds16(Kb + (size_t)(t0 * 64 + r) * 512 + kvh * 64 + c * 8, base + tid * 8);
  gload_lds16(VTb + (size_t)(kvh * 64 + r) * 2048 + t0 * 64 + c * 8, base + 4096 + tid * 8);
  gload_lds16(Kb + (size_t)(t1 * 64 + r) * 512 + kvh * 64 + c * 8, base + 8192 + tid * 8);
  gload_lds16(VTb + (size_t)(kvh * 64 + r) * 2048 + t1 * 64 + c * 8, base + 12288 + tid * 8);
}

__global__ __launch_bounds__(512, 4) void attn_kernel(
    const u16* __restrict__ Qb, const u16* __restrict__ Kb,
    const u16* __restrict__ VTb, u16* __restrict__ AOb,
    const float4* __restrict__ wo, ushort4* __restrict__ wobf) {
  // [buf 2][tile-slot 4: K_even,V_even,K_odd,V_odd][64x64 bf16] = 64 KB
  __shared__ __align__(16) u16 S[2][4][4096];
  f32x4* od = (f32x4*)&S[0][0][0];  // combine scratch overlay: 5*256*16B = 20 KB

  const int tid = threadIdx.x;
  const int l = tid & 63, w = tid >> 6;
  const int hw = w & 3, p = w >> 2;
  const int kvh = blockIdx.y;
  const int x = blockIdx.x;
  const int h = kvh * 4 + hw;
  const int g = l >> 4, lc = l & 15;
  const short8 ONES = {16256, 16256, 16256, 16256, 16256, 16256, 16256, 16256};

  // prologue: wo fp32 -> bf16 under idle HBM BW (4 chunks/thread exactly)
  {
    int gtid = (kvh * 64 + x) * 512 + tid;
#pragma unroll
    for (int i = 0; i < 4; ++i)
      wobf[gtid + i * 262144] = cvt4(wo[gtid + i * 262144]);
  }

  for (int half = 0; half < 2; ++half) {
    const int qb = half ? (127 - x) : x;
    const int qs = qb * 16;
    const int nt = (qb >> 2) + 1;
    const int np = (nt + 1) >> 1;

    // Q fragments (B-operand of swapped QK)
    const u16* qp = Qb + (size_t)(qs + lc) * 2048 + h * 64 + g * 8;
    short8 aq0 = *(const short8*)qp;
    short8 aq1 = *(const short8*)(qp + 32);

    f32x4 o[4];
    f32x4 ols = f32x4{0.f, 0.f, 0.f, 0.f};
#pragma unroll
    for (int dt = 0; dt < 4; ++dt) o[dt] = f32x4{0.f, 0.f, 0.f, 0.f};

    stage_pair(Kb, VTb, &S[0][0][0], kvh, 0, (1 < nt) ? 1 : 0, tid);

    for (int i = 0; i < np; ++i) {
      const int b = i & 1;
      // barrier1: everyone done reading buf[b^1] (prev iter) before restage
      __builtin_amdgcn_s_barrier();
      __builtin_amdgcn_sched_barrier(0);
      if (i + 1 < np) {
        int t0 = 2 * (i + 1);
        int t1 = (t0 + 1 < nt) ? (t0 + 1) : (nt - 1);  // clamp keeps count const
        stage_pair(Kb, VTb, &S[b ^ 1][0][0], kvh, t0, t1, tid);
        asm volatile("s_waitcnt vmcnt(4)" ::: "memory");  // pair(i) landed
      } else {
        asm volatile("s_waitcnt vmcnt(0)" ::: "memory");
      }
      __builtin_amdgcn_s_barrier();
      __builtin_amdgcn_sched_barrier(0);

      const int t = 2 * i + p;
      if (t < nt) {
        const u16* ks = &S[b][2 * p][0];
        const u16* vs = &S[b][2 * p + 1][0];

        // S^T[k][q] = K Q^T : lane (g,lc) holds q=lc, k = ck*16 + g*4 + r
        f32x4 s[4];
#pragma unroll
        for (int ck = 0; ck < 4; ++ck) s[ck] = f32x4{0.f, 0.f, 0.f, 0.f};
        __builtin_amdgcn_s_setprio(1);
#pragma unroll
        for (int kk = 0; kk < 2; ++kk)
#pragma unroll
          for (int ck = 0; ck < 4; ++ck) {
            short8 bk = lds_frag(ks, ck * 16 + lc, kk * 4 + g);
            s[ck] = mfma16(bk, kk ? aq1 : aq0, s[ck]);
          }
        __builtin_amdgcn_s_setprio(0);

        // causal mask on the diagonal tile (exp2(-1e30) -> 0)
        if (t == nt - 1) {
#pragma unroll
          for (int ck = 0; ck < 4; ++ck) {
            int kg = t * 64 + ck * 16 + g * 4;
            int qg = qs + lc;
#pragma unroll
            for (int r = 0; r < 4; ++r)
              if (kg + r > qg) s[ck][r] = -1e30f;
          }
        }

        // P = exp2(S) directly; pack to PV A-frags in-register
        short8 pfrag[2];
        {
          uint32_t d0[4], d1[4];
#pragma unroll
          for (int ck = 0; ck < 4; ++ck) {
            float e0 = exp2f(s[ck][0]);
            float e1 = exp2f(s[ck][1]);
            float e2 = exp2f(s[ck][2]);
            float e3 = exp2f(s[ck][3]);
            d0[ck] = cvtpk(e0, e1);
            d1[ck] = cvtpk(e2, e3);
          }
#pragma unroll
          for (int kk = 0; kk < 2; ++kk) {
            uint32_t A0 = d0[2 * kk], B0 = d0[2 * kk + 1];
            swap32(A0, B0); swap16(A0, B0);
            uint32_t A1 = d1[2 * kk], B1 = d1[2 * kk + 1];
            swap32(A1, B1); swap16(A1, B1);
            u32x4 u = {A0, A1, B0, B1};
            pfrag[kk] = __builtin_bit_cast(short8, u);
          }
        }

        // O += P V ; ls += P * ones (row-sum in row layout)
        __builtin_amdgcn_s_setprio(1);
#pragma unroll
        for (int kk = 0; kk < 2; ++kk) {
#pragma unroll
          for (int dt = 0; dt < 4; ++dt) {
            short8 bv = lds_frag(vs, dt * 16 + lc, kk * 4 + g);
            o[dt] = mfma16(pfrag[kk], bv, o[dt]);
          }
          ols = mfma16(pfrag[kk], ONES, ols);
        }
        __builtin_amdgcn_s_setprio(0);
      }
    }

    // ---- in-block combine: pure element-wise add of the two partials ----
    __builtin_amdgcn_s_barrier();  // all tile reads of S done; overlay scratch
    const int slot = hw * 64 + l;  // 0..255; 16B/lane stride -> conflict-free
    if (p == 1) {
#pragma unroll
      for (int j = 0; j < 4; ++j) od[j * 256 + slot] = o[j];
      od[4 * 256 + slot] = ols;
    }
    __builtin_amdgcn_s_barrier();
    if (p == 0) {
#pragma unroll
      for (int j = 0; j < 4; ++j) {
        f32x4 o1 = od[j * 256 + slot];
#pragma unroll
        for (int r = 0; r < 4; ++r) o[j][r] += o1[r];
      }
      f32x4 ls1 = od[4 * 256 + slot];
#pragma unroll
      for (int r = 0; r < 4; ++r) ols[r] += ls1[r];

#pragma unroll
      for (int r = 0; r < 4; ++r) {
        float inv = 1.0f / ols[r];
#pragma unroll
        for (int dt = 0; dt < 4; ++dt) {
          float v = o[dt][r] * inv;
          AOb[(size_t)(qs + g * 4 + r) * 2048 + h * 64 + dt * 16 + lc] = f2b(v);
        }
      }
    }
    __builtin_amdgcn_s_barrier();  // scratch reads done before next half stages
  }
}

// ---------- output projection GEMM, 128x64 tile, double-buffered + counted vmcnt ----------
__global__ __launch_bounds__(256) void out_gemm(
    const u16* __restrict__ A, const u16* __restrict__ W, float* __restrict__ C) {
  __shared__ __align__(16) u16 As[2][128 * 64];
  __shared__ __align__(16) u16 Bs[2][64 * 64];
  const int tid = threadIdx.x;
  const int l = tid & 63, w = tid >> 6;
  const int wm = w >> 1, wn = w & 1;
  const int bn = blockIdx.x, bm = blockIdx.y;
  const int g = l >> 4, lc = l & 15;

  f32x4 acc[4][2];
#pragma unroll
  for (int i = 0; i < 4; ++i)
#pragma unroll
    for (int j = 0; j < 2; ++j) acc[i][j] = f32x4{0.f, 0.f, 0.f, 0.f};

  const u16* Abase = A + (size_t)bm * 128 * 2048;
  const u16* Bbase = W + (size_t)bn * 64 * 2048;

#define OUT_STAGE(kt, buf)                                                      \
  {                                                                             \
    _Pragma("unroll")                                                           \
    for (int i = 0; i < 4; ++i) {                                               \
      int p = i * 256 + tid;                                                    \
      int r = p >> 3;                                                           \
      int c = (p & 7) ^ (r & 7);                                                \
      gload_lds16(Abase + (size_t)r * 2048 + (kt) * 64 + c * 8, As[buf] + p * 8); \
    }                                                                           \
    _Pragma("unroll")                                                           \
    for (int i = 0; i < 2; ++i) {                                               \
      int p = i * 256 + tid;                                                    \
      int r = p >> 3;                                                           \
      int c = (p & 7) ^ (r & 7);                                                \
      gload_lds16(Bbase + (size_t)r * 2048 + (kt) * 64 + c * 8, Bs[buf] + p * 8); \
    }                                                                           \
  }

  OUT_STAGE(0, 0);

  for (int kt = 0; kt < 32; ++kt) {
    const int b = kt & 1;
    __builtin_amdgcn_s_barrier();
    __builtin_amdgcn_sched_barrier(0);
    if (kt + 1 < 32) {
      OUT_STAGE(kt + 1, b ^ 1);
      asm volatile("s_waitcnt vmcnt(6)" ::: "memory");
    } else {
      asm volatile("s_waitcnt vmcnt(0)" ::: "memory");
    }
    __builtin_amdgcn_s_barrier();
    __builtin_amdgcn_sched_barrier(0);

#pragma unroll
    for (int kk = 0; kk < 2; ++kk) {
      short8 af[4], bfr[2];
#pragma unroll
      for (int mi = 0; mi < 4; ++mi)
        af[mi] = lds_frag(As[b], wm * 64 + mi * 16 + lc, kk * 4 + g);
#pragma unroll
      for (int ni = 0; ni < 2; ++ni)
        bfr[ni] = lds_frag(Bs[b], wn * 32 + ni * 16 + lc, kk * 4 + g);
#pragma unroll
      for (int mi = 0; mi < 4; ++mi)
#pragma unroll
        for (int ni = 0; ni < 2; ++ni)
          acc[mi][ni] = mfma16(af[mi], bfr[ni], acc[mi][ni]);
    }
  }
#undef OUT_STAGE

#pragma unroll
  for (int mi = 0; mi < 4; ++mi) {
    int srow0 = bm * 128 + wm * 64 + mi * 16 + g * 4;
#pragma unroll
    for (int ni = 0; ni < 2; ++ni) {
      int n = bn * 64 + wn * 32 + ni * 16 + lc;
#pragma unroll
      for (int r = 0; r < 4; ++r)
        C[(size_t)(srow0 + r) * 2048 + n] = acc[mi][ni][r];
    }
  }
}

// ---------- launch ----------
extern "C" void kernel_launch(void* const* d_in, const int* in_sizes, int n_in,
                              void* d_out, int out_size, void* d_ws, size_t ws_size,
                              hipStream_t stream) {
  (void)in_sizes; (void)n_in; (void)out_size; (void)ws_size;
  const float* x  = (const float*)d_in[0];
  const float* wq = (const float*)d_in[1];
  const float* wk = (const float*)d_in[2];
  const float* wv = (const float*)d_in[3];
  const float* wo = (const float*)d_in[4];
  float* out = (float*)d_out;
  char* ws = (char*)d_ws;

  u16* xbf  = (u16*)(ws + 0);
  u16* wqbf = (u16*)(ws + 8388608);
  u16* wkbf = (u16*)(ws + 16777216);
  u16* wvbf = (u16*)(ws + 18874368);
  u16* wobf = (u16*)(ws + 20971520);
  u16* Qb   = (u16*)(ws + 29360128);
  u16* Kb   = (u16*)(ws + 37748736);
  u16* VTb  = (u16*)(ws + 39845888);
  u16* AOb  = (u16*)(ws + 41943040);
  // RoPE table overlays the (dead-until-attn) AOb region.
  float2* ropeT = (float2*)(ws + 41943040);

  cvt_kernel<<<2048, 256, 0, stream>>>(
      (const float4*)x, (const float4*)wq, (const float4*)wk, (const float4*)wv,
      (ushort4*)xbf, (ushort4*)wqbf, (ushort4*)wkbf, (ushort4*)wvbf, ropeT);

  qkv_gemm<<<dim3(48, 16), 256, 0, stream>>>(xbf, wqbf, wkbf, wvbf, ropeT, Qb, Kb, VTb);

  attn_kernel<<<dim3(64, 8), 512, 0, stream>>>(Qb, Kb, VTb, AOb,
                                               (const float4*)wo, (ushort4*)wobf);

  out_gemm<<<dim3(32, 16), 256, 0, stream>>>(AOb, wobf, out);
}

// Round 18
// 116.025 us; speedup vs baseline: 1.0229x; 1.0229x over previous
//
#include <hip/hip_runtime.h>
#include <hip/hip_bf16.h>
#include <stdint.h>

#define DEVI __device__ __forceinline__

typedef unsigned short u16;
typedef __attribute__((ext_vector_type(8))) short short8;
typedef __attribute__((ext_vector_type(8))) __bf16 bf16x8;
typedef __attribute__((ext_vector_type(4))) float f32x4;
typedef __attribute__((ext_vector_type(4))) uint32_t u32x4;

// ---------- small helpers ----------
DEVI u16 f2b(float f) {
  __hip_bfloat16 h = __float2bfloat16(f);
  return __builtin_bit_cast(u16, h);
}
DEVI float b2f(u16 u) {
  union { float f; uint32_t i; } v;
  v.i = ((uint32_t)u) << 16;
  return v.f;
}

DEVI f32x4 mfma16(short8 a, short8 b, f32x4 c) {
  return __builtin_amdgcn_mfma_f32_16x16x32_bf16(
      __builtin_bit_cast(bf16x8, a), __builtin_bit_cast(bf16x8, b), c, 0, 0, 0);
}

// async global->LDS, 16B per lane; LDS dest = wave-uniform base + lane*16
DEVI void gload_lds16(const u16* g, u16* l) {
  __builtin_amdgcn_global_load_lds(
      (const __attribute__((address_space(1))) uint32_t*)g,
      (__attribute__((address_space(3))) uint32_t*)l, 16, 0, 0);
}

// Swizzled ds_read_b128 of an MFMA fragment from a [rows][64] bf16 tile
DEVI short8 lds_frag(const u16* base, int row, int col16) {
  int byte = (row << 7) ^ (col16 << 4) ^ ((row & 7) << 4);
  return *(const short8*)((const char*)base + byte);
}

// v_cvt_pk_bf16_f32: dst.lo = bf16(lo), dst.hi = bf16(hi)
DEVI uint32_t cvtpk(float lo, float hi) {
  uint32_t r;
  asm("v_cvt_pk_bf16_f32 %0, %1, %2" : "=v"(r) : "v"(lo), "v"(hi));
  return r;
}
// NOTE: operands must hold DISTINCT registers (same-value operands get
// register-coalesced -> self-swap -> silent corruption; round-4 bug).
DEVI void swap32(uint32_t& a, uint32_t& b) {
  asm("v_permlane32_swap_b32 %0, %1" : "+v"(a), "+v"(b));
}
DEVI void swap16(uint32_t& a, uint32_t& b) {
  asm("v_permlane16_swap_b32 %0, %1" : "+v"(a), "+v"(b));
}

// ---------- fp32 -> bf16 conversion of inputs + RoPE table build ----------
DEVI ushort4 cvt4(float4 v) {
  ushort4 o;
  o.x = f2b(v.x); o.y = f2b(v.y); o.z = f2b(v.z); o.w = f2b(v.w);
  return o;
}
DEVI ushort4 cvt4s(float4 v, float s) {
  ushort4 o;
  o.x = f2b(v.x * s); o.y = f2b(v.y * s); o.z = f2b(v.z * s); o.w = f2b(v.w * s);
  return o;
}

__global__ void cvt_kernel(const float4* __restrict__ x, const float4* __restrict__ wq,
                           const float4* __restrict__ wk, const float4* __restrict__ wv,
                           ushort4* __restrict__ xb, ushort4* __restrict__ wqb,
                           ushort4* __restrict__ wkb, ushort4* __restrict__ wvb,
                           float2* __restrict__ ropeT) {
  int t = blockIdx.x * blockDim.x + threadIdx.x;
  int stride = gridDim.x * blockDim.x;
  // wq pre-scaled by 0.125*log2(e): RoPE is linear, so the attention scale
  // (and the exp2 conversion factor) commutes into the Q weights.
  const float QS = 0.18033688011112042f;
  for (int i = t; i < 1048576; i += stride) xb[i]  = cvt4(x[i]);
  for (int i = t; i < 1048576; i += stride) wqb[i] = cvt4s(wq[i], QS);
  for (int i = t; i < 262144;  i += stride) wkb[i] = cvt4(wk[i]);
  for (int i = t; i < 262144;  i += stride) wvb[i] = cvt4(wv[i]);
  // RoPE table: [s 2048][ip 32] -> (cos, sin) of s * 10000^(-ip/32).
  // Lives in the (currently dead) AOb region; attn overwrites it later.
  for (int i = t; i < 65536; i += stride) {
    int s = i >> 5, ip = i & 31;
    float sn, cs;
    sincosf((float)s * exp2f(-(float)ip * 0.41524101186092034f), &sn, &cs);
    ropeT[i] = float2{cs, sn};
  }
}

// ---------- QKV projection GEMM, 128x64 tile, table-driven RoPE epilogue ----------
// r16 form: single-buffer + __syncthreads (explicit dbuf/counted-vmcnt was a
// measured null here, r17 — implicit wave overlap at 3 blocks/CU already
// hides the drain).
__global__ __launch_bounds__(256) void qkv_gemm(
    const u16* __restrict__ X, const u16* __restrict__ WQ,
    const u16* __restrict__ WK, const u16* __restrict__ WV,
    const float2* __restrict__ ropeT,
    u16* __restrict__ Qo, u16* __restrict__ Ko, u16* __restrict__ VTo) {
  __shared__ __align__(16) u16 As[128 * 64];
  __shared__ __align__(16) u16 Bs[64 * 64];
  const int tid = threadIdx.x;
  const int l = tid & 63, w = tid >> 6;
  const int wm = w >> 1, wn = w & 1;
  const int bn = blockIdx.x, bm = blockIdx.y;
  const int g = l >> 4, lc = l & 15;

  const u16* Wsrc;
  int nbase;
  if (bn < 32)      { Wsrc = WQ; nbase = bn * 64; }
  else if (bn < 40) { Wsrc = WK; nbase = bn * 64 - 2048; }
  else              { Wsrc = WV; nbase = bn * 64 - 2560; }

  f32x4 acc[4][2];
#pragma unroll
  for (int i = 0; i < 4; ++i)
#pragma unroll
    for (int j = 0; j < 2; ++j) acc[i][j] = f32x4{0.f, 0.f, 0.f, 0.f};

  const u16* Abase = X + (size_t)bm * 128 * 2048;

  for (int kt = 0; kt < 32; ++kt) {
#pragma unroll
    for (int i = 0; i < 4; ++i) {
      int p = i * 256 + tid;
      int r = p >> 3;
      int c = (p & 7) ^ (r & 7);
      gload_lds16(Abase + (size_t)r * 2048 + kt * 64 + c * 8, As + p * 8);
    }
#pragma unroll
    for (int i = 0; i < 2; ++i) {
      int p = i * 256 + tid;
      int r = p >> 3;
      int c = (p & 7) ^ (r & 7);
      gload_lds16(Wsrc + (size_t)(nbase + r) * 2048 + kt * 64 + c * 8, Bs + p * 8);
    }
    __syncthreads();
#pragma unroll
    for (int kk = 0; kk < 2; ++kk) {
      short8 af[4], bfr[2];
#pragma unroll
      for (int mi = 0; mi < 4; ++mi)
        af[mi] = lds_frag(As, wm * 64 + mi * 16 + lc, kk * 4 + g);
#pragma unroll
      for (int ni = 0; ni < 2; ++ni)
        bfr[ni] = lds_frag(Bs, wn * 32 + ni * 16 + lc, kk * 4 + g);
#pragma unroll
      for (int mi = 0; mi < 4; ++mi)
#pragma unroll
        for (int ni = 0; ni < 2; ++ni)
          acc[mi][ni] = mfma16(af[mi], bfr[ni], acc[mi][ni]);
    }
    __syncthreads();
  }

#pragma unroll
  for (int mi = 0; mi < 4; ++mi) {
    int srow0 = bm * 128 + wm * 64 + mi * 16 + g * 4;
#pragma unroll
    for (int ni = 0; ni < 2; ++ni) {
      int n = nbase + wn * 32 + ni * 16 + lc;
      f32x4 v = acc[mi][ni];
      if (bn < 40) {
        // fused RoPE: pair (2i, 2i+1) within head; partner value in lane lc^1
        int ip = (n & 63) >> 1;
        bool odd = (n & 1);
#pragma unroll
        for (int r = 0; r < 4; ++r) {
          float own = v[r];
          float par = __shfl_xor(own, 1);
          float2 cssn = ropeT[(srow0 + r) * 32 + ip];
          float res = odd ? fmaf(par, cssn.y, own * cssn.x)
                          : fmaf(own, cssn.x, -(par * cssn.y));
          if (bn < 32) Qo[(size_t)(srow0 + r) * 2048 + n] = f2b(res);
          else         Ko[(size_t)(srow0 + r) * 512 + n]  = f2b(res);
        }
      } else {
        ushort4 pk;
        pk.x = f2b(v[0]); pk.y = f2b(v[1]); pk.z = f2b(v[2]); pk.w = f2b(v[3]);
        *(ushort4*)(VTo + (size_t)n * 2048 + srow0) = pk;
      }
    }
  }
}

// ---------- causal flash attention: 8-wave in-block split-K, NO-MAX softmax ----------
// r12 hot loop verbatim. wo fp32->bf16 conversion PIPELINED through the main
// loop (1 load or 1 store per pair-iteration, 8 steps, every block has >=17
// iterations): removes the r16 prologue's first-vmcnt serialization while
// still using attn's idle HBM BW. FIFO-safe: cvt ops are always older than
// the newest 4 staging ops, so the counted vmcnt(4) retires them naturally;
// the cvt load is consumed one full iteration after issue (latency hidden).
DEVI void stage_pair(const u16* __restrict__ Kb, const u16* __restrict__ VTb,
                     u16* base, int kvh, int t0, int t1, int tid) {
  int r = tid >> 3;
  int c = (tid & 7) ^ (r & 7);
  gload_lds16(Kb + (size_t)(t0 * 64 + r) * 512 + kvh * 64 + c * 8, base + tid * 8);
  gload_lds16(VTb + (size_t)(kvh * 64 + r) * 2048 + t0 * 64 + c * 8, base + 4096 + tid * 8);
  gload_lds16(Kb + (size_t)(t1 * 64 + r) * 512 + kvh * 64 + c * 8, base + 8192 + tid * 8);
  gload_lds16(VTb + (size_t)(kvh * 64 + r) * 2048 + t1 * 64 + c * 8, base + 12288 + tid * 8);
}

__global__ __launch_bounds__(512, 4) void attn_kernel(
    const u16* __restrict__ Qb, const u16* __restrict__ Kb,
    const u16* __restrict__ VTb, u16* __restrict__ AOb,
    const float4* __restrict__ wo, ushort4* __restrict__ wobf) {
  // [buf 2][tile-slot 4: K_even,V_even,K_odd,V_odd][64x64 bf16] = 64 KB
  __shared__ __align__(16) u16 S[2][4][4096];
  f32x4* od = (f32x4*)&S[0][0][0];  // combine scratch overlay: 5*256*16B = 20 KB

  const int tid = threadIdx.x;
  const int l = tid & 63, w = tid >> 6;
  const int hw = w & 3, p = w >> 2;
  const int kvh = blockIdx.y;
  const int x = blockIdx.x;
  const int h = kvh * 4 + hw;
  const int g = l >> 4, lc = l & 15;
  const short8 ONES = {16256, 16256, 16256, 16256, 16256, 16256, 16256, 16256};

  // pipelined wo-conversion state (4 chunks per thread, load/store alternating)
  const int gtid = (kvh * 64 + x) * 512 + tid;
  int cvi = 0;
  float4 pend;

  for (int half = 0; half < 2; ++half) {
    const int qb = half ? (127 - x) : x;
    const int qs = qb * 16;
    const int nt = (qb >> 2) + 1;
    const int np = (nt + 1) >> 1;

    // Q fragments (B-operand of swapped QK)
    const u16* qp = Qb + (size_t)(qs + lc) * 2048 + h * 64 + g * 8;
    short8 aq0 = *(const short8*)qp;
    short8 aq1 = *(const short8*)(qp + 32);

    f32x4 o[4];
    f32x4 ols = f32x4{0.f, 0.f, 0.f, 0.f};
#pragma unroll
    for (int dt = 0; dt < 4; ++dt) o[dt] = f32x4{0.f, 0.f, 0.f, 0.f};

    stage_pair(Kb, VTb, &S[0][0][0], kvh, 0, (1 < nt) ? 1 : 0, tid);

    for (int i = 0; i < np; ++i) {
      const int b = i & 1;
      // barrier1: everyone done reading buf[b^1] (prev iter) before restage
      __builtin_amdgcn_s_barrier();
      __builtin_amdgcn_sched_barrier(0);
      if (i + 1 < np) {
        int t0 = 2 * (i + 1);
        int t1 = (t0 + 1 < nt) ? (t0 + 1) : (nt - 1);  // clamp keeps count const
        stage_pair(Kb, VTb, &S[b ^ 1][0][0], kvh, t0, t1, tid);
        asm volatile("s_waitcnt vmcnt(4)" ::: "memory");  // pair(i) landed
      } else {
        asm volatile("s_waitcnt vmcnt(0)" ::: "memory");
      }
      __builtin_amdgcn_s_barrier();
      __builtin_amdgcn_sched_barrier(0);

      const int t = 2 * i + p;
      if (t < nt) {
        const u16* ks = &S[b][2 * p][0];
        const u16* vs = &S[b][2 * p + 1][0];

        // S^T[k][q] = K Q^T : lane (g,lc) holds q=lc, k = ck*16 + g*4 + r
        f32x4 s[4];
#pragma unroll
        for (int ck = 0; ck < 4; ++ck) s[ck] = f32x4{0.f, 0.f, 0.f, 0.f};
        __builtin_amdgcn_s_setprio(1);
#pragma unroll
        for (int kk = 0; kk < 2; ++kk)
#pragma unroll
          for (int ck = 0; ck < 4; ++ck) {
            short8 bk = lds_frag(ks, ck * 16 + lc, kk * 4 + g);
            s[ck] = mfma16(bk, kk ? aq1 : aq0, s[ck]);
          }
        __builtin_amdgcn_s_setprio(0);

        // causal mask on the diagonal tile (exp2(-1e30) -> 0)
        if (t == nt - 1) {
#pragma unroll
          for (int ck = 0; ck < 4; ++ck) {
            int kg = t * 64 + ck * 16 + g * 4;
            int qg = qs + lc;
#pragma unroll
            for (int r = 0; r < 4; ++r)
              if (kg + r > qg) s[ck][r] = -1e30f;
          }
        }

        // P = exp2(S) directly; pack to PV A-frags in-register
        short8 pfrag[2];
        {
          uint32_t d0[4], d1[4];
#pragma unroll
          for (int ck = 0; ck < 4; ++ck) {
            float e0 = exp2f(s[ck][0]);
            float e1 = exp2f(s[ck][1]);
            float e2 = exp2f(s[ck][2]);
            float e3 = exp2f(s[ck][3]);
            d0[ck] = cvtpk(e0, e1);
            d1[ck] = cvtpk(e2, e3);
          }
#pragma unroll
          for (int kk = 0; kk < 2; ++kk) {
            uint32_t A0 = d0[2 * kk], B0 = d0[2 * kk + 1];
            swap32(A0, B0); swap16(A0, B0);
            uint32_t A1 = d1[2 * kk], B1 = d1[2 * kk + 1];
            swap32(A1, B1); swap16(A1, B1);
            u32x4 u = {A0, A1, B0, B1};
            pfrag[kk] = __builtin_bit_cast(short8, u);
          }
        }

        // O += P V ; ls += P * ones (row-sum in row layout)
        __builtin_amdgcn_s_setprio(1);
#pragma unroll
        for (int kk = 0; kk < 2; ++kk) {
#pragma unroll
          for (int dt = 0; dt < 4; ++dt) {
            short8 bv = lds_frag(vs, dt * 16 + lc, kk * 4 + g);
            o[dt] = mfma16(pfrag[kk], bv, o[dt]);
          }
          ols = mfma16(pfrag[kk], ONES, ols);
        }
        __builtin_amdgcn_s_setprio(0);
      }

      // pipelined wo-conversion: one memory op per iteration, 8 total.
      // Load chunk c at step 2c; convert+store it at step 2c+1 (one full
      // iteration in flight -> data-wait hidden).
      if (cvi < 8) {
        int c = cvi >> 1;
        if ((cvi & 1) == 0) pend = wo[gtid + c * 262144];
        else                wobf[gtid + c * 262144] = cvt4(pend);
        ++cvi;
      }
    }

    // ---- in-block combine: pure element-wise add of the two partials ----
    __builtin_amdgcn_s_barrier();  // all tile reads of S done; overlay scratch
    const int slot = hw * 64 + l;  // 0..255; 16B/lane stride -> conflict-free
    if (p == 1) {
#pragma unroll
      for (int j = 0; j < 4; ++j) od[j * 256 + slot] = o[j];
      od[4 * 256 + slot] = ols;
    }
    __builtin_amdgcn_s_barrier();
    if (p == 0) {
#pragma unroll
      for (int j = 0; j < 4; ++j) {
        f32x4 o1 = od[j * 256 + slot];
#pragma unroll
        for (int r = 0; r < 4; ++r) o[j][r] += o1[r];
      }
      f32x4 ls1 = od[4 * 256 + slot];
#pragma unroll
      for (int r = 0; r < 4; ++r) ols[r] += ls1[r];

#pragma unroll
      for (int r = 0; r < 4; ++r) {
        float inv = 1.0f / ols[r];
#pragma unroll
        for (int dt = 0; dt < 4; ++dt) {
          float v = o[dt][r] * inv;
          AOb[(size_t)(qs + g * 4 + r) * 2048 + h * 64 + dt * 16 + lc] = f2b(v);
        }
      }
    }
    __builtin_amdgcn_s_barrier();  // scratch reads done before next half stages
  }
}

// ---------- output projection GEMM, 128x64 tile (r16 form) ----------
__global__ __launch_bounds__(256) void out_gemm(
    const u16* __restrict__ A, const u16* __restrict__ W, float* __restrict__ C) {
  __shared__ __align__(16) u16 As[128 * 64];
  __shared__ __align__(16) u16 Bs[64 * 64];
  const int tid = threadIdx.x;
  const int l = tid & 63, w = tid >> 6;
  const int wm = w >> 1, wn = w & 1;
  const int bn = blockIdx.x, bm = blockIdx.y;
  const int g = l >> 4, lc = l & 15;

  f32x4 acc[4][2];
#pragma unroll
  for (int i = 0; i < 4; ++i)
#pragma unroll
    for (int j = 0; j < 2; ++j) acc[i][j] = f32x4{0.f, 0.f, 0.f, 0.f};

  const u16* Abase = A + (size_t)bm * 128 * 2048;
  const u16* Bbase = W + (size_t)bn * 64 * 2048;

  for (int kt = 0; kt < 32; ++kt) {
#pragma unroll
    for (int i = 0; i < 4; ++i) {
      int p = i * 256 + tid;
      int r = p >> 3;
      int c = (p & 7) ^ (r & 7);
      gload_lds16(Abase + (size_t)r * 2048 + kt * 64 + c * 8, As + p * 8);
    }
#pragma unroll
    for (int i = 0; i < 2; ++i) {
      int p = i * 256 + tid;
      int r = p >> 3;
      int c = (p & 7) ^ (r & 7);
      gload_lds16(Bbase + (size_t)r * 2048 + kt * 64 + c * 8, Bs + p * 8);
    }
    __syncthreads();
#pragma unroll
    for (int kk = 0; kk < 2; ++kk) {
      short8 af[4], bfr[2];
#pragma unroll
      for (int mi = 0; mi < 4; ++mi)
        af[mi] = lds_frag(As, wm * 64 + mi * 16 + lc, kk * 4 + g);
#pragma unroll
      for (int ni = 0; ni < 2; ++ni)
        bfr[ni] = lds_frag(Bs, wn * 32 + ni * 16 + lc, kk * 4 + g);
#pragma unroll
      for (int mi = 0; mi < 4; ++mi)
#pragma unroll
        for (int ni = 0; ni < 2; ++ni)
          acc[mi][ni] = mfma16(af[mi], bfr[ni], acc[mi][ni]);
    }
    __syncthreads();
  }

#pragma unroll
  for (int mi = 0; mi < 4; ++mi) {
    int srow0 = bm * 128 + wm * 64 + mi * 16 + g * 4;
#pragma unroll
    for (int ni = 0; ni < 2; ++ni) {
      int n = bn * 64 + wn * 32 + ni * 16 + lc;
#pragma unroll
      for (int r = 0; r < 4; ++r)
        C[(size_t)(srow0 + r) * 2048 + n] = acc[mi][ni][r];
    }
  }
}

// ---------- launch ----------
extern "C" void kernel_launch(void* const* d_in, const int* in_sizes, int n_in,
                              void* d_out, int out_size, void* d_ws, size_t ws_size,
                              hipStream_t stream) {
  (void)in_sizes; (void)n_in; (void)out_size; (void)ws_size;
  const float* x  = (const float*)d_in[0];
  const float* wq = (const float*)d_in[1];
  const float* wk = (const float*)d_in[2];
  const float* wv = (const float*)d_in[3];
  const float* wo = (const float*)d_in[4];
  float* out = (float*)d_out;
  char* ws = (char*)d_ws;

  u16* xbf  = (u16*)(ws + 0);
  u16* wqbf = (u16*)(ws + 8388608);
  u16* wkbf = (u16*)(ws + 16777216);
  u16* wvbf = (u16*)(ws + 18874368);
  u16* wobf = (u16*)(ws + 20971520);
  u16* Qb   = (u16*)(ws + 29360128);
  u16* Kb   = (u16*)(ws + 37748736);
  u16* VTb  = (u16*)(ws + 39845888);
  u16* AOb  = (u16*)(ws + 41943040);
  // RoPE table overlays the (dead-until-attn) AOb region.
  float2* ropeT = (float2*)(ws + 41943040);

  cvt_kernel<<<2048, 256, 0, stream>>>(
      (const float4*)x, (const float4*)wq, (const float4*)wk, (const float4*)wv,
      (ushort4*)xbf, (ushort4*)wqbf, (ushort4*)wkbf, (ushort4*)wvbf, ropeT);

  qkv_gemm<<<dim3(48, 16), 256, 0, stream>>>(xbf, wqbf, wkbf, wvbf, ropeT, Qb, Kb, VTb);

  attn_kernel<<<dim3(64, 8), 512, 0, stream>>>(Qb, Kb, VTb, AOb,
                                               (const float4*)wo, (ushort4*)wobf);

  out_gemm<<<dim3(32, 16), 256, 0, stream>>>(AOb, wobf, out);
}